// Round 6
// baseline (207.395 us; speedup 1.0000x reference)
//
#include <hip/hip_runtime.h>

#define F 128
#define HPAD 136   // bf16 row stride in LDS (272 B: 16B-aligned, breaks pow2 banks)

typedef short bf16x8 __attribute__((ext_vector_type(8)));   // 8 bf16 = 4 VGPRs
typedef float f32x4  __attribute__((ext_vector_type(4)));

__device__ __forceinline__ unsigned short f2bf(float f) {
    unsigned int u = __float_as_uint(f);
    u += 0x7fffu + ((u >> 16) & 1u);        // round-to-nearest-even
    return (unsigned short)(u >> 16);
}
__device__ __forceinline__ float bf2f(unsigned short s) {
    return __uint_as_float(((unsigned int)s) << 16);
}

// ---------------- init: zero counts + convert x->bf16 + pack W ----------------
// grid covers n*16 threads (one per 8 floats of x)
__global__ __launch_bounds__(256) void init_kernel(const float* __restrict__ x,
                                                   unsigned short* __restrict__ xh,
                                                   const float* __restrict__ Ws,
                                                   const float* __restrict__ Wn,
                                                   unsigned short* __restrict__ Bpack,
                                                   int* __restrict__ counts, int n) {
    int idx = blockIdx.x * 256 + threadIdx.x;

    if (idx < n) counts[idx] = 0;

    if (idx < 32768) {   // B-fragment pack: [Ws;Wn] (256x128) bf16
        int j    = idx & 7;
        int lane = (idx >> 3) & 63;
        int tile = idx >> 9;        // 0..63
        int s = tile >> 3;
        int t = tile & 7;
        int k = s * 32 + (lane >> 4) * 8 + j;
        int c = t * 16 + (lane & 15);
        float v = (k < F) ? Ws[k * F + c] : Wn[(k - F) * F + c];
        Bpack[idx] = f2bf(v);
    }

    if (idx < n * 16) {  // convert 8 floats -> bf16x8
        int node = idx >> 4;
        int c = (idx & 15) * 8;
        const float4* p = (const float4*)(x + (size_t)node * F + c);
        float4 v0 = p[0], v1 = p[1];
        bf16x8 o;
        o[0] = (short)f2bf(v0.x); o[1] = (short)f2bf(v0.y);
        o[2] = (short)f2bf(v0.z); o[3] = (short)f2bf(v0.w);
        o[4] = (short)f2bf(v1.x); o[5] = (short)f2bf(v1.y);
        o[6] = (short)f2bf(v1.z); o[7] = (short)f2bf(v1.w);
        *(bf16x8*)(xh + (size_t)node * F + c) = o;
    }
}

// ---------------- histogram of dst ----------------
__global__ __launch_bounds__(256) void hist_kernel(const int* __restrict__ dst,
                                                   int* __restrict__ counts, int E) {
    int e = blockIdx.x * blockDim.x + threadIdx.x;
    if (e < E) atomicAdd(&counts[dst[e]], 1);
}

// ---------------- scan phase 1: per-block (1024 elems) scan + raw block sums ----------------
__global__ __launch_bounds__(256) void scan_local_kernel(const int* __restrict__ counts,
                                                         int* __restrict__ offsets,
                                                         int* __restrict__ bsums, int n) {
    __shared__ int wsum[4];
    int tid = threadIdx.x;
    int base = blockIdx.x * 1024 + tid * 4;
    int4 c = make_int4(0, 0, 0, 0);
    if (base + 3 < n) c = *(const int4*)(counts + base);
    else if (base < n) {
        c.x = counts[base];
        if (base + 1 < n) c.y = counts[base + 1];
        if (base + 2 < n) c.z = counts[base + 2];
    }
    int tsum = c.x + c.y + c.z + c.w;
    int lane = tid & 63, wid = tid >> 6;
    int v = tsum;
    #pragma unroll
    for (int off = 1; off < 64; off <<= 1) {
        int t = __shfl_up(v, off);
        if (lane >= off) v += t;
    }
    if (lane == 63) wsum[wid] = v;
    __syncthreads();
    int wexcl = 0;
    #pragma unroll
    for (int w = 0; w < 3; ++w) if (w < wid) wexcl += wsum[w];
    int texcl = wexcl + v - tsum;
    int4 o;
    o.x = texcl;
    o.y = o.x + c.x;
    o.z = o.y + c.y;
    o.w = o.z + c.z;
    if (base + 3 < n) *(int4*)(offsets + base) = o;
    else if (base < n) {
        offsets[base] = o.x;
        if (base + 1 < n) offsets[base + 1] = o.y;
        if (base + 2 < n) offsets[base + 2] = o.z;
    }
    if (tid == 255) bsums[blockIdx.x] = wexcl + v;   // RAW block total
}

// ---------------- scan phase 2 (folded): add block offsets; each block scans bsums itself ----------------
// assumes gridDim.x == nb <= 64
__global__ __launch_bounds__(256) void scan_add_kernel(int* __restrict__ offsets,
                                                       const int* __restrict__ bsums,
                                                       int* __restrict__ cursor, int n, int nb) {
    __shared__ int boff_s, total_s;
    int tid = threadIdx.x;
    if (tid < 64) {
        int orig = (tid < nb) ? bsums[tid] : 0;
        int v = orig;
        #pragma unroll
        for (int off = 1; off < 64; off <<= 1) {
            int t = __shfl_up(v, off);
            if ((tid & 63) >= off) v += t;
        }
        if (tid == 63) total_s = v;
        if (tid == (int)blockIdx.x) boff_s = v - orig;   // exclusive prefix for this block
    }
    __syncthreads();
    int boff = boff_s;
    if (blockIdx.x == 0 && tid == 0) offsets[n] = total_s;   // == E

    int base = (blockIdx.x * 256 + tid) * 4;
    if (base >= n) return;
    if (base + 3 < n) {
        int4 v = *(const int4*)(offsets + base);
        v.x += boff; v.y += boff; v.z += boff; v.w += boff;
        *(int4*)(offsets + base) = v;
        *(int4*)(cursor + base) = v;
    } else {
        for (int j = 0; j < 4 && base + j < n; ++j) {
            int v = offsets[base + j] + boff;
            offsets[base + j] = v;
            cursor[base + j] = v;
        }
    }
}

// ---------------- fill CSR buckets ----------------
__global__ __launch_bounds__(256) void fill_kernel(const int* __restrict__ src,
                                                   const int* __restrict__ dst,
                                                   int* __restrict__ cursor,
                                                   int* __restrict__ esrc, int E) {
    int e = blockIdx.x * blockDim.x + threadIdx.x;
    if (e < E) {
        int p = atomicAdd(&cursor[dst[e]], 1);
        esrc[p] = src[e];
    }
}

// ---------------- fused aggregate + MFMA GEMM ----------------
// block = 64 nodes. Phase A: h = mean of gathered bf16 x rows -> LDS.
// Phase B: out = relu([x | h] @ Bpack + b). A-frags k=0..127 from global xh,
// k=128..255 from LDS hs.
__global__ __launch_bounds__(256) void agg_gemm_kernel(
        const unsigned short* __restrict__ xh,      // n x 128 bf16
        const int* __restrict__ esrc,
        const int* __restrict__ offsets,
        const unsigned short* __restrict__ Bpack,
        const float* __restrict__ bias,
        float* __restrict__ out, int n) {
    __shared__ __align__(16) unsigned short hs[64 * HPAD];

    int tid = threadIdx.x;
    int row0blk = blockIdx.x * 64;

    // ---- phase A: 16 lanes per node, 16 nodes per pass, 4 passes ----
    int l16 = tid & 15;
    int g16 = tid >> 4;
    #pragma unroll
    for (int p = 0; p < 4; ++p) {
        int lr = p * 16 + g16;          // local row 0..63
        int v = row0blk + lr;
        float acc[8] = {0.f, 0.f, 0.f, 0.f, 0.f, 0.f, 0.f, 0.f};
        if (v < n) {
            int beg = offsets[v];
            int end = offsets[v + 1];
            for (int j = beg; j < end; ++j) {
                int s = esrc[j];
                bf16x8 xv = *(const bf16x8*)(xh + (size_t)s * F + l16 * 8);
                #pragma unroll
                for (int i = 0; i < 8; ++i) acc[i] += bf2f((unsigned short)xv[i]);
            }
            float r = (end > beg) ? 1.0f / (float)(end - beg) : 0.f;
            #pragma unroll
            for (int i = 0; i < 8; ++i) acc[i] *= r;
        }
        bf16x8 o;
        #pragma unroll
        for (int i = 0; i < 8; ++i) o[i] = (short)f2bf(acc[i]);
        *(bf16x8*)(&hs[lr * HPAD + l16 * 8]) = o;
    }
    __syncthreads();

    // ---- phase B: wave = 32 rows x 64 cols ----
    int wave = tid >> 6;
    int lane = tid & 63;
    int q = lane >> 4;
    int m = lane & 15;
    int rowhalf = (wave & 1) * 32;
    int coltile = (wave >> 1) * 4;
    int row0 = row0blk + rowhalf;

    f32x4 acc2[2][4];
    #pragma unroll
    for (int r = 0; r < 2; ++r)
        #pragma unroll
        for (int t = 0; t < 4; ++t) acc2[r][t] = 0.f;

    int r0 = min(row0 + m, n - 1);
    int r1 = min(row0 + 16 + m, n - 1);
    const unsigned short* a0p = xh + (size_t)r0 * F + q * 8;
    const unsigned short* a1p = xh + (size_t)r1 * F + q * 8;
    const unsigned short* h0p = &hs[(rowhalf + m) * HPAD + q * 8];
    const unsigned short* h1p = &hs[(rowhalf + 16 + m) * HPAD + q * 8];

    #pragma unroll
    for (int s = 0; s < 8; ++s) {
        bf16x8 a0 = (s < 4) ? *(const bf16x8*)(a0p + s * 32)
                            : *(const bf16x8*)(h0p + (s - 4) * 32);
        bf16x8 a1 = (s < 4) ? *(const bf16x8*)(a1p + s * 32)
                            : *(const bf16x8*)(h1p + (s - 4) * 32);
        #pragma unroll
        for (int t = 0; t < 4; ++t) {
            bf16x8 bf = *(const bf16x8*)(Bpack + ((size_t)((s * 8 + coltile + t) * 64 + lane)) * 8);
            acc2[0][t] = __builtin_amdgcn_mfma_f32_16x16x32_bf16(a0, bf, acc2[0][t], 0, 0, 0);
            acc2[1][t] = __builtin_amdgcn_mfma_f32_16x16x32_bf16(a1, bf, acc2[1][t], 0, 0, 0);
        }
    }

    #pragma unroll
    for (int r = 0; r < 2; ++r)
        #pragma unroll
        for (int t = 0; t < 4; ++t) {
            int col = (coltile + t) * 16 + m;
            float bv = bias[col];
            #pragma unroll
            for (int g = 0; g < 4; ++g) {
                int row = row0 + r * 16 + q * 4 + g;
                if (row < n)
                    out[(size_t)row * F + col] = fmaxf(acc2[r][t][g] + bv, 0.f);
            }
        }
}

extern "C" void kernel_launch(void* const* d_in, const int* in_sizes, int n_in,
                              void* d_out, int out_size, void* d_ws, size_t ws_size,
                              hipStream_t stream) {
    const float* x  = (const float*)d_in[0];
    const float* Ws = (const float*)d_in[1];
    const float* Wn = (const float*)d_in[2];
    const float* b  = (const float*)d_in[3];
    const int* src  = (const int*)d_in[4];
    const int* dst  = (const int*)d_in[5];
    int n = in_sizes[0] / F;      // 50000
    int E = in_sizes[4];          // 600000

    int nb = (n + 1023) / 1024;   // 49 (must be <= 64 for scan_add_kernel)

    // workspace layout (4B elems):
    //   xh      : n*128 bf16 (x only)     12.8 MB
    //   counts  : n ints
    //   offsets : n+1 ints
    //   cursor  : n ints
    //   esrc    : E ints
    //   bsums   : nb ints
    //   Bpack   : 32768 bf16 (64 KB)
    unsigned short* xh = (unsigned short*)d_ws;
    int* counts  = (int*)(xh + (size_t)n * F);
    int* offsets = counts + n;
    int* cursor  = offsets + (n + 1);
    int* esrc    = cursor + n;
    int* bsums   = esrc + E;
    unsigned short* Bpack = (unsigned short*)(bsums + nb);

    float* out = (float*)d_out;

    init_kernel<<<(n * 16 + 255) / 256, 256, 0, stream>>>(x, xh, Ws, Wn, Bpack, counts, n);
    hist_kernel<<<(E + 255) / 256, 256, 0, stream>>>(dst, counts, E);
    scan_local_kernel<<<nb, 256, 0, stream>>>(counts, offsets, bsums, n);
    scan_add_kernel<<<nb, 256, 0, stream>>>(offsets, bsums, cursor, n, nb);
    fill_kernel<<<(E + 255) / 256, 256, 0, stream>>>(src, dst, cursor, esrc, E);
    agg_gemm_kernel<<<(n + 63) / 64, 256, 0, stream>>>(xh, esrc, offsets, Bpack, b, out, n);
}